// Round 2
// baseline (497.793 us; speedup 1.0000x reference)
//
#include <hip/hip_runtime.h>
#include <hip/hip_bf16.h>
#include <math.h>

#define BB 64
#define NN 4096
#define II 8
#define CC 32
#define DD 16
#define CJ 512           // CC*DD
#define EPSQ 1e-7f

// ws layout: [ Ocum : BB*CJ f32 ][ S : BB*CJ f32 ][ hat bf16 : bchunk*NN*CJ*2 ]
// bchunk chosen adaptively so everything fits in ws_size. Routing is
// independent per b, so the batch is processed in bchunk-sized chunks.

__device__ __forceinline__ unsigned f2bf(float f) {
    unsigned u = __float_as_uint(f);
    return (u + 0x7fffu + ((u >> 16) & 1u)) >> 16;   // RNE
}

__global__ __launch_bounds__(256) void zero_kernel(float* __restrict__ p, int count) {
    int i = blockIdx.x * 256 + threadIdx.x;
    if (i < count) p[i] = 0.f;
}

// One block per n. LDS: W[:,n,:,:] (4096 f32) + x[bofs:bofs+bcount, n, :].
// Thread t computes cj = 2t, 2t+1 for each b in chunk; packs bf16x2.
__global__ __launch_bounds__(256) void hat_kernel(const float* __restrict__ x,
                                                  const float* __restrict__ W,
                                                  unsigned* __restrict__ hatu,
                                                  int bofs, int bcount) {
    const int n = blockIdx.x;
    const int t = threadIdx.x;
    __shared__ float Wl[CJ * II];   // [cj][i], cj = c*16 + j
    __shared__ float xl[BB * II];   // [b_local][i]

    #pragma unroll
    for (int k = 0; k < 4; ++k) {
        int f = 4 * (t + 256 * k);          // flat (c,j,i) = cj*8+i
        int c = f >> 7;                     // /128
        int r = f & 127;
        const float4 v = *reinterpret_cast<const float4*>(
            W + (size_t)c * (NN * 128) + (size_t)n * 128 + r);
        *reinterpret_cast<float4*>(Wl + f) = v;
    }
    if (t < 2 * bcount) {
        int bl = t >> 1, half = t & 1;
        const float4 v = *reinterpret_cast<const float4*>(
            x + (size_t)(bofs + bl) * (NN * II) + (size_t)n * II + half * 4);
        *reinterpret_cast<float4*>(xl + bl * 8 + half * 4) = v;
    }
    __syncthreads();

    float w0[8], w1[8];
    #pragma unroll
    for (int i = 0; i < 8; ++i) {
        w0[i] = Wl[(2 * t) * 8 + i];
        w1[i] = Wl[(2 * t + 1) * 8 + i];
    }
    for (int bl = 0; bl < bcount; ++bl) {
        float xv[8];
        *reinterpret_cast<float4*>(xv)     = *reinterpret_cast<const float4*>(xl + bl * 8);
        *reinterpret_cast<float4*>(xv + 4) = *reinterpret_cast<const float4*>(xl + bl * 8 + 4);
        float d0 = 0.f, d1 = 0.f;
        #pragma unroll
        for (int i = 0; i < 8; ++i) {
            d0 = fmaf(w0[i], xv[i], d0);
            d1 = fmaf(w1[i], xv[i], d1);
        }
        hatu[((size_t)bl * NN + n) * 256 + t] = f2bf(d0) | (f2bf(d1) << 16);
    }
}

// One routing sweep over one b-chunk. block = (b_local, n-chunk of 256).
// wave w handles n = n0+w, step 4. lane l owns cj = l*8..l*8+7 (c = l>>1).
// Exact softmax over the 32 c's: pair-sum (xor 1) then parity-class
// butterfly (xor 2..32 — each parity class holds each c exactly once).
__global__ __launch_bounds__(256) void pass_kernel(const unsigned* __restrict__ hatu,
                                                   const float* __restrict__ Ocum,
                                                   float* __restrict__ S,
                                                   int bofs) {
    const int bl = blockIdx.x >> 4;
    const int chunk = blockIdx.x & 15;
    const int bg = bofs + bl;
    const int t = threadIdx.x;
    const int lane = t & 63, wave = t >> 6;
    __shared__ float red[4 * CJ];

    const int cjb = lane * 8;
    float oc[8];
    #pragma unroll
    for (int k = 0; k < 8; ++k) oc[k] = Ocum[bg * CJ + cjb + k];
    float acc[8] = {0.f, 0.f, 0.f, 0.f, 0.f, 0.f, 0.f, 0.f};

    const int n0 = chunk * 256;
    for (int n = n0 + wave; n < n0 + 256; n += 4) {
        const uint4 hv = *reinterpret_cast<const uint4*>(
            hatu + ((size_t)bl * NN + n) * 256 + lane * 4);
        float h[8];
        h[0] = __uint_as_float(hv.x << 16);
        h[1] = __uint_as_float(hv.x & 0xffff0000u);
        h[2] = __uint_as_float(hv.y << 16);
        h[3] = __uint_as_float(hv.y & 0xffff0000u);
        h[4] = __uint_as_float(hv.z << 16);
        h[5] = __uint_as_float(hv.z & 0xffff0000u);
        h[6] = __uint_as_float(hv.w << 16);
        h[7] = __uint_as_float(hv.w & 0xffff0000u);

        float p = 0.f;
        #pragma unroll
        for (int k = 0; k < 8; ++k) p = fmaf(h[k], oc[k], p);
        p += __shfl_xor(p, 1, 64);          // full logit for c = lane>>1

        float m = p;
        #pragma unroll
        for (int o = 2; o < 64; o <<= 1) m = fmaxf(m, __shfl_xor(m, o, 64));
        float e = __expf(p - m);
        float s = e;
        #pragma unroll
        for (int o = 2; o < 64; o <<= 1) s += __shfl_xor(s, o, 64);
        float cc = e / s;

        #pragma unroll
        for (int k = 0; k < 8; ++k) acc[k] = fmaf(cc, h[k], acc[k]);
    }

    #pragma unroll
    for (int k = 0; k < 8; ++k) red[wave * CJ + cjb + k] = acc[k];
    __syncthreads();
    for (int cj = t; cj < CJ; cj += 256) {
        float v = red[cj] + red[CJ + cj] + red[2 * CJ + cj] + red[3 * CJ + cj];
        atomicAdd(&S[bl * CJ + cj], v);
    }
}

// squash(S) -> out_t; Ocum += out_t; final pass writes d_out.
__global__ __launch_bounds__(256) void squash_kernel(const float* __restrict__ S,
                                                     float* __restrict__ Ocum,
                                                     float* __restrict__ out,
                                                     int writeOut, int bofs, int bcount) {
    int idx = blockIdx.x * 256 + threadIdx.x;   // local (b_local*CC + c)
    if (idx >= bcount * CC) return;
    int gidx = idx + bofs * CC;                 // global (b*CC + c)
    float v[DD];
    float s2 = 0.f;
    #pragma unroll
    for (int j = 0; j < DD; ++j) {
        v[j] = S[idx * DD + j];
        s2 = fmaf(v[j], v[j], s2);
    }
    float scale = (s2 / (1.f + s2)) / sqrtf(s2 + EPSQ);
    #pragma unroll
    for (int j = 0; j < DD; ++j) {
        float o = scale * v[j];
        Ocum[gidx * DD + j] += o;
        if (writeOut) out[gidx * DD + j] = o;
    }
}

extern "C" void kernel_launch(void* const* d_in, const int* in_sizes, int n_in,
                              void* d_out, int out_size, void* d_ws, size_t ws_size,
                              hipStream_t stream) {
    const float* x = (const float*)d_in[0];
    const float* W = (const float*)d_in[1];
    float* out = (float*)d_out;

    char* ws = (char*)d_ws;
    float* Ocum = (float*)ws;                         // BB*CJ f32
    float* S = Ocum + BB * CJ;                        // BB*CJ f32 (max)
    unsigned* hat = (unsigned*)(ws + (size_t)2 * BB * CJ * sizeof(float));
    const size_t small_bytes = (size_t)2 * BB * CJ * sizeof(float);   // 256 KB

    int bchunk = BB;
    while (bchunk > 1 &&
           small_bytes + (size_t)bchunk * NN * CJ * 2 > ws_size)
        bchunk >>= 1;

    zero_kernel<<<(BB * CJ + 255) / 256, 256, 0, stream>>>(Ocum, BB * CJ);

    for (int bofs = 0; bofs < BB; bofs += bchunk) {
        hat_kernel<<<NN, 256, 0, stream>>>(x, W, hat, bofs, bchunk);
        for (int pass = 0; pass < 3; ++pass) {
            zero_kernel<<<(bchunk * CJ + 255) / 256, 256, 0, stream>>>(S, bchunk * CJ);
            pass_kernel<<<bchunk * 16, 256, 0, stream>>>(hat, Ocum, S, bofs);
            squash_kernel<<<(bchunk * CC + 255) / 256, 256, 0, stream>>>(
                S, Ocum, out, pass == 2 ? 1 : 0, bofs, bchunk);
        }
    }
}

// Round 4
// 290.488 us; speedup vs baseline: 1.7136x; 1.7136x over previous
//
#include <hip/hip_runtime.h>
#include <math.h>

// CapsuleLayer dynamic routing, fully fused (no hat materialization).
// B=64, N=4096, I=8, C=32, D=16, 3 routing iterations.
//
// Key identity: routing logits are linear in the running sum of outputs:
//   b_t[b,c,n] = (sum_{s<t} out_s[b,c,:]) . hat[b,c,n,:]  == Ocum . hat
// so each routing pass is ONE sweep over (n), recomputing hat = W.x on the
// fly with packed-f16 dot2 (reads W 64 MiB + x 8 MiB instead of hat 256 MiB).
//
// fused_pass: grid 256 blocks x 1024 thr. Block owns 16 consecutive n.
//   Wave w owns b in {w, w+16, w+32, w+48}; lane l owns c=l>>1, j-octet=l&1
//   (cj = l*8..l*8+7). Per n: W[:,n,:,:] staged to LDS as f16 (8 KB,
//   double-buffered, 16B-unit swizzle u^=(u>>3)&7 so per-lane 128 B fragment
//   reads are conflict-free). hat via v_dot2_f32_f16; softmax over the 32 c
//   via 1+5 shfl_xor (no max subtraction: |logit| <= ~7); acc in packed f16.
//   Block writes f16 partials; reduce_a + squash_b finish the reduction,
//   squash, and Ocum update.
//
// ws: [partial f16 16 MiB][partial2 f32 512 KB][Ocum f32 128 KB]

typedef __fp16 h2 __attribute__((ext_vector_type(2)));   // native type of cvt_pkrtz / fdot2

#define NN 4096
#define RN 16            // n per fused block
#define NBLK (NN / RN)   // 256

union U32H2 { unsigned u; h2 h; };

__device__ __forceinline__ float4 wload(const float* __restrict__ W, int n, int t) {
    int f = 4 * t;               // flat f16-tile index (c*128 + j*8 + i)
    int c = f >> 7;
    int r = f & 127;
    return *reinterpret_cast<const float4*>(W + (size_t)c * 524288 + (size_t)n * 128 + r);
}

__device__ __forceinline__ void wstore(__fp16* buf, int t, float4 v) {
    int u = t >> 1;                      // logical 16B unit = f>>3
    int up = u ^ ((u >> 3) & 7);         // bank swizzle
    __fp16* p = buf + up * 8 + (t & 1) * 4;
    __fp16 q[4] = {(__fp16)v.x, (__fp16)v.y, (__fp16)v.z, (__fp16)v.w};
    *reinterpret_cast<float2*>(p) = *reinterpret_cast<float2*>(q);
}

__global__ __launch_bounds__(1024) void fused_pass(const float* __restrict__ x,
                                                   const float* __restrict__ W,
                                                   const float* __restrict__ Ocum,
                                                   unsigned short* __restrict__ partial,
                                                   int uniform) {
    const int n0 = blockIdx.x * RN;
    const int t = threadIdx.x;
    const int lane = t & 63, w = t >> 6;
    __shared__ __align__(16) __fp16 Wl[2][4096];
    __shared__ __align__(16) __fp16 xl[64 * 128];   // [b][r*8+i]

    // stage x slice (f32 -> f16): thread t -> (b = t>>4, r = t&15)
    {
        int b = t >> 4, r = t & 15;
        const float* xp = x + (size_t)b * 32768 + (size_t)(n0 + r) * 8;
        float4 v0 = *reinterpret_cast<const float4*>(xp);
        float4 v1 = *reinterpret_cast<const float4*>(xp + 4);
        __fp16 q[8] = {(__fp16)v0.x, (__fp16)v0.y, (__fp16)v0.z, (__fp16)v0.w,
                       (__fp16)v1.x, (__fp16)v1.y, (__fp16)v1.z, (__fp16)v1.w};
        *reinterpret_cast<float4*>(&xl[b * 128 + r * 8]) = *reinterpret_cast<float4*>(q);
    }
    wstore(Wl[0], t, wload(W, n0, t));

    // per-wave state: Ocum fragments (f16x2) and accumulators
    h2 oc[4][4];
    h2 acc[4][4];
    #pragma unroll
    for (int kb = 0; kb < 4; ++kb)
        #pragma unroll
        for (int jp = 0; jp < 4; ++jp) {
            acc[kb][jp] = (h2)(__fp16)0.f;
            oc[kb][jp] = (h2)(__fp16)0.f;
        }
    if (!uniform) {
        #pragma unroll
        for (int kb = 0; kb < 4; ++kb) {
            int b = w + 16 * kb;
            const float* op = Ocum + (size_t)b * 512 + lane * 8;
            float4 o0 = *reinterpret_cast<const float4*>(op);
            float4 o1 = *reinterpret_cast<const float4*>(op + 4);
            oc[kb][0] = __builtin_amdgcn_cvt_pkrtz(o0.x, o0.y);
            oc[kb][1] = __builtin_amdgcn_cvt_pkrtz(o0.z, o0.w);
            oc[kb][2] = __builtin_amdgcn_cvt_pkrtz(o1.x, o1.y);
            oc[kb][3] = __builtin_amdgcn_cvt_pkrtz(o1.z, o1.w);
        }
    }
    __syncthreads();

    const int l8 = lane * 8, lx = lane & 7;
    for (int r = 0; r < RN; ++r) {
        float4 wnext;
        if (r + 1 < RN) wnext = wload(W, n0 + r + 1, t);

        // lane's W fragment: 8 x 16B units (j = joct*8 + k, i = 0..7)
        const float4* bq = reinterpret_cast<const float4*>(Wl[r & 1]);
        float4 wv[8];
        #pragma unroll
        for (int k = 0; k < 8; ++k) wv[k] = bq[l8 + (k ^ lx)];
        const h2* wh = reinterpret_cast<const h2*>(wv);

        #pragma unroll
        for (int kb = 0; kb < 4; ++kb) {
            int b = w + 16 * kb;
            float4 xv = *reinterpret_cast<const float4*>(&xl[b * 128 + r * 8]);
            const h2* xh = reinterpret_cast<const h2*>(&xv);

            float h[8];
            #pragma unroll
            for (int j = 0; j < 8; ++j) {
                float s = __builtin_amdgcn_fdot2(wh[j * 4 + 0], xh[0], 0.f, false);
                s = __builtin_amdgcn_fdot2(wh[j * 4 + 1], xh[1], s, false);
                s = __builtin_amdgcn_fdot2(wh[j * 4 + 2], xh[2], s, false);
                h[j] = __builtin_amdgcn_fdot2(wh[j * 4 + 3], xh[3], s, false);
            }
            h2 hh[4];
            #pragma unroll
            for (int jp = 0; jp < 4; ++jp)
                hh[jp] = __builtin_amdgcn_cvt_pkrtz(h[2 * jp], h[2 * jp + 1]);

            float ccf;
            if (uniform) {
                ccf = 0.03125f;
            } else {
                float p = __builtin_amdgcn_fdot2(oc[kb][0], hh[0], 0.f, false);
                p = __builtin_amdgcn_fdot2(oc[kb][1], hh[1], p, false);
                p = __builtin_amdgcn_fdot2(oc[kb][2], hh[2], p, false);
                p = __builtin_amdgcn_fdot2(oc[kb][3], hh[3], p, false);
                p += __shfl_xor(p, 1, 64);      // full logit for c = lane>>1
                float e = __expf(p);            // no max-sub: |p| bounded small
                float s = e;
                s += __shfl_xor(s, 2, 64);
                s += __shfl_xor(s, 4, 64);
                s += __shfl_xor(s, 8, 64);
                s += __shfl_xor(s, 16, 64);
                s += __shfl_xor(s, 32, 64);
                ccf = e / s;
            }
            h2 cc2;
            cc2.x = (__fp16)ccf;
            cc2.y = cc2.x;
            #pragma unroll
            for (int jp = 0; jp < 4; ++jp) acc[kb][jp] += hh[jp] * cc2;
        }

        if (r + 1 < RN) wstore(Wl[(r + 1) & 1], t, wnext);
        __syncthreads();
    }

    // write f16 partials: lane owns cj = lane*8..+7 for each of its 4 b
    #pragma unroll
    for (int kb = 0; kb < 4; ++kb) {
        int b = w + 16 * kb;
        *reinterpret_cast<float4*>(partial + (size_t)blockIdx.x * 32768 + b * 512 + lane * 8) =
            *reinterpret_cast<float4*>(&acc[kb][0]);
    }
}

// Sum 64 partial-blocks per group g (4 groups): partial2[g][32768] f32.
__global__ __launch_bounds__(256) void reduce_a(const unsigned short* __restrict__ partial,
                                                float* __restrict__ partial2) {
    const int g = blockIdx.x >> 6;
    const int tid2 = (blockIdx.x & 63) * 256 + threadIdx.x;   // h2 index, 0..16383
    const unsigned* pu = reinterpret_cast<const unsigned*>(partial);
    float s0 = 0.f, s1 = 0.f;
    #pragma unroll 8
    for (int pb = g * 64; pb < g * 64 + 64; ++pb) {
        U32H2 v;
        v.u = pu[(size_t)pb * 16384 + tid2];
        s0 += (float)v.h.x;
        s1 += (float)v.h.y;
    }
    float2 o;
    o.x = s0;
    o.y = s1;
    *reinterpret_cast<float2*>(partial2 + (size_t)g * 32768 + tid2 * 2) = o;
}

// Final sum of 4 groups + squash + Ocum update (+ out on last pass).
__global__ __launch_bounds__(256) void squash_b(const float* __restrict__ partial2,
                                                float* __restrict__ Ocum,
                                                float* __restrict__ out,
                                                int passIdx) {
    const int tid2 = blockIdx.x * 256 + threadIdx.x;   // 0..16383 (j-pair)
    float vx = 0.f, vy = 0.f;
    #pragma unroll
    for (int g = 0; g < 4; ++g) {
        float2 pv = *reinterpret_cast<const float2*>(partial2 + (size_t)g * 32768 + tid2 * 2);
        vx += pv.x;
        vy += pv.y;
    }
    float s2 = vx * vx + vy * vy;                 // norm over 16 j = 8 threads
    s2 += __shfl_xor(s2, 1, 64);
    s2 += __shfl_xor(s2, 2, 64);
    s2 += __shfl_xor(s2, 4, 64);
    float scale = (s2 / (1.f + s2)) / sqrtf(s2 + 1e-7f);
    float o0 = scale * vx, o1 = scale * vy;
    float* oc = Ocum + (size_t)tid2 * 2;
    if (passIdx == 0) {
        oc[0] = o0;
        oc[1] = o1;
    } else {
        oc[0] += o0;
        oc[1] += o1;
    }
    if (passIdx == 2) {
        out[tid2 * 2] = o0;
        out[tid2 * 2 + 1] = o1;
    }
}

extern "C" void kernel_launch(void* const* d_in, const int* in_sizes, int n_in,
                              void* d_out, int out_size, void* d_ws, size_t ws_size,
                              hipStream_t stream) {
    const float* x = (const float*)d_in[0];
    const float* W = (const float*)d_in[1];
    float* out = (float*)d_out;

    char* ws = (char*)d_ws;
    unsigned short* partial = (unsigned short*)ws;                       // 256*32768 f16 = 16 MiB
    float* partial2 = (float*)(ws + (size_t)256 * 32768 * 2);            // 4*32768 f32 = 512 KiB
    float* Ocum = (float*)(ws + (size_t)256 * 32768 * 2 + (size_t)4 * 32768 * 4);  // 128 KiB

    for (int pass = 0; pass < 3; ++pass) {
        fused_pass<<<NBLK, 1024, 0, stream>>>(x, W, Ocum, partial, pass == 0 ? 1 : 0);
        reduce_a<<<256, 256, 0, stream>>>(partial, partial2);
        squash_b<<<64, 256, 0, stream>>>(partial2, Ocum, out, pass);
    }
}